// Round 1
// baseline (219.889 us; speedup 1.0000x reference)
//
#include <hip/hip_runtime.h>
#include <hip/hip_bf16.h>

// Problem: B=32, N=4096, D=128, E=24576
//   score[b,e] = dot(x[b,src[e]],Ws) + dot(x[b,dst[e]],Wd) + bias
//   out[b,dst[e]] += sigmoid(score) * x[b,src[e]]
//
// Plan: build CSR-by-dst in ws each launch (ws is re-poisoned every call),
// precompute per-node dots, then atomic-free gather: one wave per (b,n).

#define NN 4096
#define BB 32
#define DD 128

__global__ __launch_bounds__(256) void zero_deg_k(int* __restrict__ deg) {
    deg[blockIdx.x * 256 + threadIdx.x] = 0;
}

__global__ __launch_bounds__(256) void count_k(const int* __restrict__ dst,
                                               int* __restrict__ deg, int E) {
    int e = blockIdx.x * 256 + threadIdx.x;
    if (e < E) atomicAdd(&deg[dst[e]], 1);
}

// Single block: exclusive scan of 4096 degrees -> rowptr[4097], cursor copy.
__global__ __launch_bounds__(256) void scan_k(const int* __restrict__ deg,
                                              int* __restrict__ rowptr,
                                              int* __restrict__ cursor) {
    __shared__ int part[256];
    const int t = threadIdx.x;
    const int base = t * 16;
    int local[16];
    int s = 0;
    for (int k = 0; k < 16; ++k) { local[k] = deg[base + k]; s += local[k]; }
    part[t] = s;
    __syncthreads();
    for (int off = 1; off < 256; off <<= 1) {
        int v = (t >= off) ? part[t - off] : 0;
        __syncthreads();
        part[t] += v;
        __syncthreads();
    }
    int run = part[t] - s;  // exclusive prefix for this thread's chunk
    for (int k = 0; k < 16; ++k) {
        rowptr[base + k] = run;
        cursor[base + k] = run;
        run += local[k];
    }
    if (t == 255) rowptr[NN] = run;
}

__global__ __launch_bounds__(256) void scatter_k(const int* __restrict__ src,
                                                 const int* __restrict__ dst,
                                                 int* __restrict__ cursor,
                                                 int* __restrict__ srclist, int E) {
    int e = blockIdx.x * 256 + threadIdx.x;
    if (e < E) {
        int pos = atomicAdd(&cursor[dst[e]], 1);
        srclist[pos] = src[e];
    }
}

// One wave per (b,n): dsrc[b,n] = dot(x[b,n],Ws); ddst[b,n] = dot(x[b,n],Wd)
__global__ __launch_bounds__(256) void dots_k(const float* __restrict__ x,
                                              const float* __restrict__ W,
                                              float* __restrict__ dsrc,
                                              float* __restrict__ ddst) {
    const int wid  = blockIdx.x * 4 + (threadIdx.x >> 6);  // b*N+n
    const int lane = threadIdx.x & 63;
    const float2 v  = *reinterpret_cast<const float2*>(x + (size_t)wid * DD + lane * 2);
    const float2 ws = *reinterpret_cast<const float2*>(W + lane * 2);
    const float2 wd = *reinterpret_cast<const float2*>(W + DD + lane * 2);
    float ps = v.x * ws.x + v.y * ws.y;
    float pd = v.x * wd.x + v.y * wd.y;
    for (int off = 32; off; off >>= 1) {
        ps += __shfl_xor(ps, off, 64);
        pd += __shfl_xor(pd, off, 64);
    }
    if (lane == 0) {
        dsrc[wid] = ps;
        ddst[wid] = pd;
    }
}

// One wave per (b,n): accumulate over incoming edges, single coalesced write.
__global__ __launch_bounds__(256) void gather_k(const float* __restrict__ x,
                                                const int* __restrict__ rowptr,
                                                const int* __restrict__ srclist,
                                                const float* __restrict__ dsrc,
                                                const float* __restrict__ ddst,
                                                const float* __restrict__ bptr,
                                                float* __restrict__ out) {
    const int wid  = blockIdx.x * 4 + (threadIdx.x >> 6);  // b*N+n (n fastest)
    const int lane = threadIdx.x & 63;
    const int b = wid >> 12;   // /4096
    const int n = wid & (NN - 1);
    const float bias = bptr[0];
    const float sdst = ddst[wid];
    const float* xb = x + (size_t)b * NN * DD;
    const float* dsb = dsrc + (size_t)b * NN;
    float2 acc = make_float2(0.f, 0.f);
    const int beg = rowptr[n];
    const int end = rowptr[n + 1];
    for (int e = beg; e < end; ++e) {
        const int s = srclist[e];
        const float sc = dsb[s] + sdst + bias;
        const float a = 1.0f / (1.0f + __expf(-sc));
        const float2 v = *reinterpret_cast<const float2*>(xb + (size_t)s * DD + lane * 2);
        acc.x += a * v.x;
        acc.y += a * v.y;
    }
    *reinterpret_cast<float2*>(out + (size_t)wid * DD + lane * 2) = acc;
}

extern "C" void kernel_launch(void* const* d_in, const int* in_sizes, int n_in,
                              void* d_out, int out_size, void* d_ws, size_t ws_size,
                              hipStream_t stream) {
    const float* x    = (const float*)d_in[0];
    const int*   ei   = (const int*)d_in[1];
    const float* W    = (const float*)d_in[2];
    const float* bias = (const float*)d_in[3];
    float* out = (float*)d_out;

    const int E = in_sizes[1] / 2;
    const int* src = ei;
    const int* dst = ei + E;

    // workspace carve (all 256B-aligned chunks)
    int* rowptr  = (int*)d_ws;               // NN+1
    int* cursor  = rowptr + (NN + 64);       // NN
    int* deg     = cursor + NN;              // NN
    int* srclist = deg + NN;                 // E
    float* dsrc  = (float*)(srclist + ((E + 63) & ~63));  // BB*NN
    float* ddst  = dsrc + BB * NN;                        // BB*NN

    zero_deg_k<<<NN / 256, 256, 0, stream>>>(deg);
    count_k<<<(E + 255) / 256, 256, 0, stream>>>(dst, deg, E);
    scan_k<<<1, 256, 0, stream>>>(deg, rowptr, cursor);
    scatter_k<<<(E + 255) / 256, 256, 0, stream>>>(src, dst, cursor, srclist, E);
    dots_k<<<BB * NN / 4, 256, 0, stream>>>(x, W, dsrc, ddst);
    gather_k<<<BB * NN / 4, 256, 0, stream>>>(x, rowptr, srclist, dsrc, ddst, bias, out);
}

// Round 2
// 173.580 us; speedup vs baseline: 1.2668x; 1.2668x over previous
//
#include <hip/hip_runtime.h>
#include <hip/hip_bf16.h>

// Problem: B=32, N=4096, D=128, E=24576
//   score[b,e] = dot(x[b,src[e]],Ws) + dot(x[b,dst[e]],Wd) + bias
//   out[b,dst[e]] += sigmoid(score) * x[b,src[e]]
//
// CSR-by-dst built in ws each launch; per-node dots precomputed; gather is
// atomic-free, one wave per (b,n), edges pipelined 8-deep, batch->XCD swizzle.

#define NN 4096
#define BB 32
#define DD 128

__global__ __launch_bounds__(256) void zero_deg_k(int* __restrict__ deg) {
    deg[blockIdx.x * 256 + threadIdx.x] = 0;
}

__global__ __launch_bounds__(256) void count_k(const int* __restrict__ dst,
                                               int* __restrict__ deg, int E) {
    int e = blockIdx.x * 256 + threadIdx.x;
    if (e < E) atomicAdd(&deg[dst[e]], 1);
}

// Single block: exclusive scan of 4096 degrees -> rowptr[4097], cursor copy.
__global__ __launch_bounds__(256) void scan_k(const int* __restrict__ deg,
                                              int* __restrict__ rowptr,
                                              int* __restrict__ cursor) {
    __shared__ int part[256];
    const int t = threadIdx.x;
    const int base = t * 16;
    int local[16];
    int s = 0;
    for (int k = 0; k < 16; ++k) { local[k] = deg[base + k]; s += local[k]; }
    part[t] = s;
    __syncthreads();
    for (int off = 1; off < 256; off <<= 1) {
        int v = (t >= off) ? part[t - off] : 0;
        __syncthreads();
        part[t] += v;
        __syncthreads();
    }
    int run = part[t] - s;
    for (int k = 0; k < 16; ++k) {
        rowptr[base + k] = run;
        cursor[base + k] = run;
        run += local[k];
    }
    if (t == 255) rowptr[NN] = run;
}

__global__ __launch_bounds__(256) void scatter_k(const int* __restrict__ src,
                                                 const int* __restrict__ dst,
                                                 int* __restrict__ cursor,
                                                 int* __restrict__ srclist, int E) {
    int e = blockIdx.x * 256 + threadIdx.x;
    if (e < E) {
        int pos = atomicAdd(&cursor[dst[e]], 1);
        srclist[pos] = src[e];
    }
}

// 2 rows per wave: lanes [0,32) row0, [32,64) row1; float4 loads; 5-round reduce.
__global__ __launch_bounds__(256) void dots_k(const float* __restrict__ x,
                                              const float* __restrict__ W,
                                              float* __restrict__ dsrc,
                                              float* __restrict__ ddst) {
    const int row  = blockIdx.x * 8 + (threadIdx.x >> 5);  // b*N+n
    const int l    = threadIdx.x & 31;
    const float4 v  = *reinterpret_cast<const float4*>(x + (size_t)row * DD + l * 4);
    const float4 ws = *reinterpret_cast<const float4*>(W + l * 4);
    const float4 wd = *reinterpret_cast<const float4*>(W + DD + l * 4);
    float ps = v.x * ws.x + v.y * ws.y + v.z * ws.z + v.w * ws.w;
    float pd = v.x * wd.x + v.y * wd.y + v.z * wd.z + v.w * wd.w;
    // xor offsets 1..16 keep bit5 fixed -> reduction stays within each 32-lane half
    for (int off = 16; off; off >>= 1) {
        ps += __shfl_xor(ps, off, 64);
        pd += __shfl_xor(pd, off, 64);
    }
    if (l == 0) {
        dsrc[row] = ps;
        ddst[row] = pd;
    }
}

// One wave per (b,n). Edges processed in 8-deep pipelined chunks:
// lanes 0..7 fetch srclist + score, broadcast via shfl (-> scalar), then 8
// independent 512B row loads in flight. Batch->XCD swizzle keeps x[b] (2 MiB)
// resident in one XCD's 4 MiB L2.
__global__ __launch_bounds__(256) void gather_k(const float* __restrict__ x,
                                                const int* __restrict__ rowptr,
                                                const int* __restrict__ srclist,
                                                const float* __restrict__ dsrc,
                                                const float* __restrict__ ddst,
                                                const float* __restrict__ bptr,
                                                float* __restrict__ out) {
    // bijective swizzle: slot -> (b, nblk) with b&7 == slot&7 (XCD heuristic)
    const int slot = blockIdx.x;            // 0..32767
    const int xcd  = slot & 7;
    const int idx  = slot >> 3;             // 0..4095
    const int b    = ((idx >> 10) << 3) | xcd;   // 0..31
    const int nblk = idx & 1023;            // 0..1023
    const int wave = threadIdx.x >> 6;
    const int lane = threadIdx.x & 63;
    const int n    = nblk * 4 + wave;
    const int wid  = (b << 12) | n;

    const float bias = bptr[0];
    const float sdst = ddst[wid];
    const float* xb  = x + (size_t)b * NN * DD;
    const float* dsb = dsrc + (size_t)b * NN;

    float2 acc = make_float2(0.f, 0.f);
    const int beg = rowptr[n];
    const int end = rowptr[n + 1];

    for (int e0 = beg; e0 < end; e0 += 8) {
        const int cnt = end - e0;           // >=1
        int   s_l = 0;
        float a_l = 0.f;
        if (lane < cnt && lane < 8) {
            s_l = srclist[e0 + lane];
            const float sc = dsb[s_l] + sdst + bias;
            a_l = 1.0f / (1.0f + __expf(-sc));
        }
#pragma unroll
        for (int j = 0; j < 8; ++j) {
            const int   s = __shfl(s_l, j, 64);
            const float a = __shfl(a_l, j, 64);
            // dead slots: a==0, s==0 (in-bounds L2-hit load, zero contribution)
            const float2 v = *reinterpret_cast<const float2*>(xb + (size_t)s * DD + lane * 2);
            acc.x += a * v.x;
            acc.y += a * v.y;
        }
    }
    *reinterpret_cast<float2*>(out + (size_t)wid * DD + lane * 2) = acc;
}

extern "C" void kernel_launch(void* const* d_in, const int* in_sizes, int n_in,
                              void* d_out, int out_size, void* d_ws, size_t ws_size,
                              hipStream_t stream) {
    const float* x    = (const float*)d_in[0];
    const int*   ei   = (const int*)d_in[1];
    const float* W    = (const float*)d_in[2];
    const float* bias = (const float*)d_in[3];
    float* out = (float*)d_out;

    const int E = in_sizes[1] / 2;
    const int* src = ei;
    const int* dst = ei + E;

    int* rowptr  = (int*)d_ws;               // NN+1
    int* cursor  = rowptr + (NN + 64);       // NN
    int* deg     = cursor + NN;              // NN
    int* srclist = deg + NN;                 // E
    float* dsrc  = (float*)(srclist + ((E + 63) & ~63));  // BB*NN
    float* ddst  = dsrc + BB * NN;                        // BB*NN

    zero_deg_k<<<NN / 256, 256, 0, stream>>>(deg);
    count_k<<<(E + 255) / 256, 256, 0, stream>>>(dst, deg, E);
    scan_k<<<1, 256, 0, stream>>>(deg, rowptr, cursor);
    scatter_k<<<(E + 255) / 256, 256, 0, stream>>>(src, dst, cursor, srclist, E);
    dots_k<<<BB * NN / 8, 256, 0, stream>>>(x, W, dsrc, ddst);
    gather_k<<<BB * NN / 4, 256, 0, stream>>>(x, rowptr, srclist, dsrc, ddst, bias, out);
}